// Round 16
// baseline (203.617 us; speedup 1.0000x reference)
//
#include <hip/hip_runtime.h>

typedef __bf16 bf16_t;
typedef __bf16 bf16x4 __attribute__((ext_vector_type(4)));
typedef __bf16 bf16x8 __attribute__((ext_vector_type(8)));
typedef float  f32x4  __attribute__((ext_vector_type(4)));

#define B_SZ  16
#define L_SEQ 2048
#define D_H   64
#define QB    64
#define KB    128
#define NQT   (L_SEQ / QB)   // 32

// softmax is over (S/8); fold log2(e)/8 into Q so MFMA output is in log2 units
#define QSCALE 0.18033688011112043f

// V: 0 = real kernel (writes Og). 1 = no-staging ablation. 3 = no-softmax ablation.
// Ablation variants write o/l to Wout (ws) to stay DCE-proof; REPS repeats the whole
// qt workload to lift variant dispatch durations above the ~43us fill dispatches.
template<int V, int REPS>
__global__ __launch_bounds__(256, 2)
void attn_abl(const float* __restrict__ Qg, const float* __restrict__ Kg,
              const float* __restrict__ Vg, float* __restrict__ Og,
              float* __restrict__ Wout)
{
    const int lin  = blockIdx.x;          // 0..511
    const int xcd  = lin & 7;
    const int slot = lin >> 3;
    const int half = slot >> 5;
    const int qi   = slot & 31;
    const int b    = xcd * 2 + half;
    const int qt   = half ? qi : (31 - qi);

    const int tid  = threadIdx.x;
    const int lane = tid & 63;
    const int lg   = lane >> 4;
    const int lc   = lane & 15;

    __shared__ __align__(16) bf16_t K_lds[2][KB][72];
    __shared__ __align__(16) bf16_t Vt_lds[2][D_H][136];

    const size_t bbase = (size_t)b * L_SEQ * D_H;

    // ---- Q fragment (B-operand of swapped QK) ----
    const int qrow = qt * QB + (tid >> 6) * 16 + lc;
    bf16x8 qa[2];
#pragma unroll
    for (int h = 0; h < 2; ++h) {
        const float* qp = Qg + bbase + (size_t)qrow * D_H + h * 32 + lg * 8;
        const f32x4 f0 = *reinterpret_cast<const f32x4*>(qp);
        const f32x4 f1 = *reinterpret_cast<const f32x4*>(qp + 4);
        bf16x8 a;
#pragma unroll
        for (int j = 0; j < 4; ++j) { a[j] = (bf16_t)(f0[j] * QSCALE); a[4 + j] = (bf16_t)(f1[j] * QSCALE); }
        qa[h] = a;
    }

    const int nkt = (qt + 2) >> 1;

    const int vkb  = tid & 31;
    const int vdg  = tid >> 5;
    const int vpos = ((vkb >> 3) << 5) + ((vkb & 3) << 3) + (((vkb >> 2) & 1) << 2);

    f32x4 kreg[8], vreg[8];

    auto issueK = [&](int kt) {
        const int kbase = kt * KB;
#pragma unroll
        for (int i = 0; i < 8; ++i) {
            const int f = i * 256 + tid;
            const int r = f >> 4, c4 = (f & 15) * 4;
            kreg[i] = *reinterpret_cast<const f32x4*>(Kg + bbase + (size_t)(kbase + r) * D_H + c4);
        }
    };
    auto issueV = [&](int kt) {
        const int kbase = kt * KB;
#pragma unroll
        for (int d2 = 0; d2 < 2; ++d2)
#pragma unroll
            for (int i = 0; i < 4; ++i)
                vreg[d2 * 4 + i] = *reinterpret_cast<const f32x4*>(
                    Vg + bbase + (size_t)(kbase + vkb * 4 + i) * D_H + (vdg + d2 * 8) * 4);
    };
    auto writeK = [&](int buf) {
#pragma unroll
        for (int i = 0; i < 8; ++i) {
            const int f = i * 256 + tid;
            const int r = f >> 4, c4 = (f & 15) * 4;
            bf16x4 k4 = { (bf16_t)kreg[i][0], (bf16_t)kreg[i][1], (bf16_t)kreg[i][2], (bf16_t)kreg[i][3] };
            *reinterpret_cast<bf16x4*>(&K_lds[buf][r][c4]) = k4;
        }
    };
    auto writeV = [&](int buf) {
#pragma unroll
        for (int d2 = 0; d2 < 2; ++d2) {
            const int db = vdg + d2 * 8;
#pragma unroll
            for (int j = 0; j < 4; ++j) {
                bf16x4 cj = { (bf16_t)vreg[d2 * 4 + 0][j], (bf16_t)vreg[d2 * 4 + 1][j],
                              (bf16_t)vreg[d2 * 4 + 2][j], (bf16_t)vreg[d2 * 4 + 3][j] };
                *reinterpret_cast<bf16x4*>(&Vt_lds[buf][db * 4 + j][vpos]) = cj;
            }
        }
    };

    f32x4 o[4];
    float m = -1e30f, l = 0.f;

    for (int rep = 0; rep < REPS; ++rep) {
#pragma unroll
        for (int dt = 0; dt < 4; ++dt) o[dt] = (f32x4){0.f, 0.f, 0.f, 0.f};
        m = -1e30f; l = 0.f;

        issueK(0); issueV(0); writeK(0); writeV(0);
        __syncthreads();
        int cur = 0;
        for (int kt = 0; kt < nkt; ++kt) {
            const bool last = (kt == nkt - 1);
            const int kbase = kt * KB;
            if constexpr (V != 1) { if (!last) issueK(kt + 1); }

            // ---- S^T = K Q^T ----
            f32x4 sc[8];
            __builtin_amdgcn_s_setprio(1);
#pragma unroll
            for (int n = 0; n < 8; ++n) {
                f32x4 acc = (f32x4){0.f, 0.f, 0.f, 0.f};
#pragma unroll
                for (int h = 0; h < 2; ++h) {
                    const bf16x8 kb = *reinterpret_cast<const bf16x8*>(&K_lds[cur][n * 16 + lc][h * 32 + lg * 8]);
                    acc = __builtin_amdgcn_mfma_f32_16x16x32_bf16(kb, qa[h], acc, 0, 0, 0);
                }
                sc[n] = acc;
            }
            __builtin_amdgcn_s_setprio(0);
            if constexpr (V != 1) { if (!last) issueV(kt + 1); }
            if (last) {
#pragma unroll
                for (int n = 0; n < 8; ++n)
#pragma unroll
                    for (int r = 0; r < 4; ++r)
                        if (kbase + n * 16 + lg * 4 + r > qrow) sc[n][r] = -1e30f;
            }

            bf16x8 w[4];
            if constexpr (V == 3) {
                // ---- ablated softmax: no max tree, no shuffles, no exp2, no rescale.
                //      keep pack + sum so w and l stay live. ----
                float rs = 0.f;
#pragma unroll
                for (int n = 0; n < 8; ++n) {
                    const float p0 = sc[n][0], p1 = sc[n][1];
                    const float p2 = sc[n][2], p3 = sc[n][3];
                    rs += (p0 + p1) + (p2 + p3);
                    const int wi = n >> 1, off = (n & 1) * 4;
                    w[wi][off + 0] = (bf16_t)p0; w[wi][off + 1] = (bf16_t)p1;
                    w[wi][off + 2] = (bf16_t)p2; w[wi][off + 3] = (bf16_t)p3;
                }
                l += rs;
            } else {
                // ---- full r4 softmax ----
                float mx = -1e30f;
#pragma unroll
                for (int n = 0; n < 8; ++n)
                    mx = fmaxf(fmaxf(mx, sc[n][0]), fmaxf(sc[n][1], fmaxf(sc[n][2], sc[n][3])));
                mx = fmaxf(mx, __shfl_xor(mx, 16));
                mx = fmaxf(mx, __shfl_xor(mx, 32));
                const float mn = fmaxf(m, mx);
                const float alpha = exp2f(m - mn);
                m = mn;
                float rs = 0.f;
#pragma unroll
                for (int n = 0; n < 8; ++n) {
                    const float p0 = exp2f(sc[n][0] - mn), p1 = exp2f(sc[n][1] - mn);
                    const float p2 = exp2f(sc[n][2] - mn), p3 = exp2f(sc[n][3] - mn);
                    rs += (p0 + p1) + (p2 + p3);
                    const int wi = n >> 1, off = (n & 1) * 4;
                    w[wi][off + 0] = (bf16_t)p0; w[wi][off + 1] = (bf16_t)p1;
                    w[wi][off + 2] = (bf16_t)p2; w[wi][off + 3] = (bf16_t)p3;
                }
                rs += __shfl_xor(rs, 16);
                rs += __shfl_xor(rs, 32);
                l = l * alpha + rs;
#pragma unroll
                for (int dt = 0; dt < 4; ++dt)
#pragma unroll
                    for (int r = 0; r < 4; ++r) o[dt][r] *= alpha;
            }

            if constexpr (V != 1) { if (!last) writeK(cur ^ 1); }

            // ---- O^T += V^T P ----
            __builtin_amdgcn_s_setprio(1);
#pragma unroll
            for (int ks = 0; ks < 4; ++ks) {
#pragma unroll
                for (int dt = 0; dt < 4; ++dt) {
                    const bf16x8 vb = *reinterpret_cast<const bf16x8*>(&Vt_lds[cur][dt * 16 + lc][ks * 32 + lg * 8]);
                    o[dt] = __builtin_amdgcn_mfma_f32_16x16x32_bf16(vb, w[ks], o[dt], 0, 0, 0);
                }
            }
            __builtin_amdgcn_s_setprio(0);

            if constexpr (V != 1) { if (!last) writeV(cur ^ 1); }
            __syncthreads();
            cur ^= 1;
        }
    }

    if constexpr (V == 0) {
        const float inv = 1.0f / l;
#pragma unroll
        for (int dt = 0; dt < 4; ++dt) {
            f32x4 val = { o[dt][0] * inv, o[dt][1] * inv, o[dt][2] * inv, o[dt][3] * inv };
            *reinterpret_cast<f32x4*>(Og + bbase + (size_t)qrow * D_H + dt * 16 + lg * 4) = val;
        }
    } else {
        // keep all results live; ws scratch, never read back
        float* wp = Wout + (((size_t)V * 512 + lin) * 256 + tid) * 20;
#pragma unroll
        for (int dt = 0; dt < 4; ++dt)
            *reinterpret_cast<f32x4*>(wp + dt * 4) = o[dt];
        wp[16] = l;
        wp[17] = m;
    }
}

extern "C" void kernel_launch(void* const* d_in, const int* in_sizes, int n_in,
                              void* d_out, int out_size, void* d_ws, size_t ws_size,
                              hipStream_t stream)
{
    const float* Q = (const float*)d_in[0];
    const float* K = (const float*)d_in[1];
    const float* V = (const float*)d_in[2];
    float* O = (float*)d_out;
    float* W = (float*)d_ws;

    // real kernel first: correctness + known 39.7us baseline
    attn_abl<0, 1><<<dim3(512), dim3(256), 0, stream>>>(Q, K, V, O, W);

    // ablation probes (write only ws); 3 reps each to rank above fill dispatches
    const size_t need = (size_t)4 * 512 * 256 * 20 * sizeof(float);   // ~42 MB
    if (ws_size >= need) {
        attn_abl<1, 3><<<dim3(512), dim3(256), 0, stream>>>(Q, K, V, O, W);  // no staging
        attn_abl<3, 3><<<dim3(512), dim3(256), 0, stream>>>(Q, K, V, O, W);  // no softmax
    }
}

// Round 17
// 39.510 us; speedup vs baseline: 5.1535x; 5.1535x over previous
//
#include <hip/hip_runtime.h>

typedef __bf16 bf16_t;
typedef __bf16 bf16x4 __attribute__((ext_vector_type(4)));
typedef __bf16 bf16x8 __attribute__((ext_vector_type(8)));
typedef float  f32x4  __attribute__((ext_vector_type(4)));

#define B_SZ  16
#define L_SEQ 2048
#define D_H   64
#define QB    128
#define KB    128
#define NT128 16                 // L_SEQ / KB
#define TILE_HW (KB * D_H)       // 8192 bf16 per tile image (16 KB)
#define IMG_ELEMS ((size_t)B_SZ * NT128 * TILE_HW)   // per tensor

// softmax is over (S/8); fold log2(e)/8 into Q so MFMA output is in log2 units
#define QSCALE 0.18033688011112043f

#define GLD_LDS16(g, l) __builtin_amdgcn_global_load_lds(                       \
    (const __attribute__((address_space(1))) void*)(g),                         \
    (__attribute__((address_space(3))) void*)(l), 16, 0, 0)

// ---------------- preproc: bf16 + transpose(V) + XOR-swizzle baked into ws images ----
__global__ __launch_bounds__(256)
void preproc_kernel(const float* __restrict__ Kg, const float* __restrict__ Vg,
                    bf16_t* __restrict__ Kimg, bf16_t* __restrict__ Vimg)
{
    const int kt = blockIdx.x, b = blockIdx.y, z = blockIdx.z;   // z = quarter
    const int t  = threadIdx.x;
    const size_t src = (size_t)b * L_SEQ * D_H + (size_t)kt * KB * D_H;
    bf16_t* ko = Kimg + (size_t)(b * NT128 + kt) * TILE_HW;
    bf16_t* vo = Vimg + (size_t)(b * NT128 + kt) * TILE_HW;

    {
        const int u = z * 256 + t, r = u >> 3, ch = u & 7;
        const float* p = Kg + src + r * 64 + ch * 8;
        const f32x4 a = *reinterpret_cast<const f32x4*>(p);
        const f32x4 c = *reinterpret_cast<const f32x4*>(p + 4);
        bf16x8 kk;
#pragma unroll
        for (int j = 0; j < 4; ++j) { kk[j] = (bf16_t)a[j]; kk[4 + j] = (bf16_t)c[j]; }
        *reinterpret_cast<bf16x8*>(&ko[r * 64 + ((ch ^ (r & 7)) << 3)]) = kk;
    }
    {
        const int d = t & 63, pc = (t >> 6) + z * 4;
        bf16x8 vv;
#pragma unroll
        for (int pw = 0; pw < 8; ++pw) {
            const int pos = pc * 8 + pw;
            const int vkb = ((pos >> 3) & 3) | (((pos >> 2) & 1) << 2) | (((pos >> 5) & 3) << 3);
            const int k   = (vkb << 2) | (pos & 3);
            vv[pw] = (bf16_t)Vg[src + (size_t)k * 64 + d];
        }
        *reinterpret_cast<bf16x8*>(&vo[d * 128 + ((pc ^ (d & 7)) << 3)]) = vv;
    }
}

// ---------------- main kernel: 8-wave QB=128 engine, pair K-split, counted-vmcnt pipeline ----
// pair p (0..7): tileL = 15-p (nktL = 16-p in 9..16), tileS = p (nktS = p+1 in 1..8)
// role 0 (front): tileL chunks 0..8                      (9 iters) -> partial
// role 1 (back):  tileL chunks 9..nktL-1 + all of tileS  (8 iters) -> partial + direct
// 3-deep LDS pipeline, raw s_barrier, s_waitcnt vmcnt(4) (never 0 mid-loop): each tile's
// fetch has ~2 compute phases to arrive; no per-iteration drain.
__global__ __launch_bounds__(512, 1)
void attn_split_kernel(const float* __restrict__ Qg, float* __restrict__ Og,
                       const bf16_t* __restrict__ Kimg, const bf16_t* __restrict__ Vimg,
                       float* __restrict__ Opart, float* __restrict__ MLb)
{
    const int lin  = blockIdx.x;          // 0..255
    const int xcd  = lin & 7;
    const int b    = xcd * 2 + ((lin >> 3) & 1);   // 2 batches per XCD -> images in L2
    const int p    = (lin >> 4) & 7;
    const int role = lin >> 7;            // both roles of a pair land on the same XCD

    const int nktL = 16 - p;
    const int nktS = p + 1;
    const int cnt1 = role ? (nktL - 9) : 9;   // tileL iters this block
    const int cnt2 = role ? nktS : 0;
    const int total = cnt1 + cnt2;            // 9 (front) / 8 (back)
    const int ktoff = role ? 9 : 0;

    const int tid  = threadIdx.x;
    const int wave = tid >> 6;             // 0..7
    const int lane = tid & 63;
    const int lg   = lane >> 4;
    const int lc   = lane & 15;
    const int lc7  = lc & 7;

    __shared__ __align__(16) bf16_t K_lds[3][TILE_HW];    // 48 KB
    __shared__ __align__(16) bf16_t Vt_lds[3][TILE_HW];   // 48 KB

    const size_t bbase = (size_t)b * L_SEQ * D_H;
    const bf16_t* kimg = Kimg + (size_t)b * NT128 * TILE_HW;
    const bf16_t* vimg = Vimg + (size_t)b * NT128 * TILE_HW;

    auto stage = [&](int kt, int buf) {
        const bf16_t* ks = kimg + (size_t)kt * TILE_HW;
        const bf16_t* vs = vimg + (size_t)kt * TILE_HW;
#pragma unroll
        for (int i = 0; i < 2; ++i) {
            const int c = wave * 2 + i;                    // chunk 0..15 (512 bf16)
            GLD_LDS16(ks + c * 512 + lane * 8, &K_lds[buf][c * 512]);
            GLD_LDS16(vs + c * 512 + lane * 8, &Vt_lds[buf][c * 512]);
        }
    };

    bf16x8 qa[2];
    auto loadQ = [&](int qt_) -> int {
        const int qr = qt_ * QB + wave * 16 + lc;
#pragma unroll
        for (int h = 0; h < 2; ++h) {
            const float* qp = Qg + bbase + (size_t)qr * D_H + h * 32 + lg * 8;
            const f32x4 f0 = *reinterpret_cast<const f32x4*>(qp);
            const f32x4 f1 = *reinterpret_cast<const f32x4*>(qp + 4);
            bf16x8 a;
#pragma unroll
            for (int j = 0; j < 4; ++j) { a[j] = (bf16_t)(f0[j] * QSCALE); a[4 + j] = (bf16_t)(f1[j] * QSCALE); }
            qa[h] = a;
        }
        return qr;
    };

    int qt = 15 - p, nktCur = nktL;
    int qrow = loadQ(qt);

    f32x4 o[4];
#pragma unroll
    for (int dt = 0; dt < 4; ++dt) o[dt] = (f32x4){0.f, 0.f, 0.f, 0.f};
    float m = -1e30f, l = 0.f;   // per-lane l partial in frame m

    auto writePartialL = [&]() {
        float lr = l;
        lr += __shfl_xor(lr, 16);
        lr += __shfl_xor(lr, 32);
        const int slot = (b * 8 + p) * 2 + role;
        float* ob = Opart + (size_t)slot * (QB * D_H);
        const int qL = wave * 16 + lc;   // 0..127
#pragma unroll
        for (int dt = 0; dt < 4; ++dt)
            *reinterpret_cast<f32x4*>(&ob[qL * 64 + dt * 16 + lg * 4]) = o[dt];
        if (lg == 0) { MLb[slot * 256 + qL] = m; MLb[slot * 256 + 128 + qL] = lr; }
    };

    auto seqKt = [&](int j) { return j < cnt1 ? ktoff + j : j - cnt1; };

    // ---- prologue: 2 tiles in flight ----
    stage(seqKt(0), 0);
    stage(seqKt(1), 1);

    for (int j = 0; j < total; ++j) {
        // Counted wait (T4): the newest 4 VMEM ops per thread are always the most
        // recent stage's, so vmcnt(4) completes everything older — incl. tile j's
        // loads and any straddle stores/Q-loads. Never drain to 0 mid-loop.
        if (j < total - 1) asm volatile("s_waitcnt vmcnt(4)" ::: "memory");
        else               asm volatile("s_waitcnt vmcnt(0)" ::: "memory");
        __builtin_amdgcn_s_barrier();          // raw barrier: no implicit drain
        asm volatile("" ::: "memory");

        if (role && j == cnt1) {
            // finalize tileL partial (possibly empty), switch to tileS
            writePartialL();
            qt = p; nktCur = nktS; qrow = loadQ(qt);
#pragma unroll
            for (int dt = 0; dt < 4; ++dt) o[dt] = (f32x4){0.f, 0.f, 0.f, 0.f};
            m = -1e30f; l = 0.f;
        }
        if (j + 2 < total) stage(seqKt(j + 2), (j + 2) % 3);   // issue AFTER barrier

        const int jb  = j % 3;
        const int kt  = seqKt(j);
        const int kb0 = kt * KB;

        // ---- S^T = K Q^T (log2 units): sc[n][r] = S[k=kb0+n*16+lg*4+r][q=qrow] ----
        f32x4 sc[8];
        __builtin_amdgcn_s_setprio(1);
#pragma unroll
        for (int n = 0; n < 8; ++n) {
            f32x4 acc = (f32x4){0.f, 0.f, 0.f, 0.f};
#pragma unroll
            for (int h = 0; h < 2; ++h) {
                const int hw = (n * 16 + lc) * 64 + ((((h << 2) | lg) ^ lc7) << 3);
                const bf16x8 kkb = *reinterpret_cast<const bf16x8*>(&K_lds[jb][hw]);
                acc = __builtin_amdgcn_mfma_f32_16x16x32_bf16(kkb, qa[h], acc, 0, 0, 0);
            }
            sc[n] = acc;
        }
        __builtin_amdgcn_s_setprio(0);
        if (kt == nktCur - 1) {   // diagonal chunk of this tile: causal mask
#pragma unroll
            for (int n = 0; n < 8; ++n)
#pragma unroll
                for (int r = 0; r < 4; ++r)
                    if (kb0 + n * 16 + lg * 4 + r > qrow) sc[n][r] = -1e30f;
        }

        // ---- defer-max online softmax (per-lane; cross-lane only on slow path) ----
        float mxp = fmaxf(fmaxf(sc[0][0], sc[0][1]), fmaxf(sc[0][2], sc[0][3]));
#pragma unroll
        for (int n = 1; n < 8; ++n)
            mxp = fmaxf(mxp, fmaxf(fmaxf(sc[n][0], sc[n][1]), fmaxf(sc[n][2], sc[n][3])));
        if (!__all(mxp <= m + 8.0f)) {
            float mx = mxp;
            mx = fmaxf(mx, __shfl_xor(mx, 16));
            mx = fmaxf(mx, __shfl_xor(mx, 32));
            const float mn = fmaxf(m, mx);
            const float alpha = exp2f(m - mn);
            m = mn;
            l *= alpha;
#pragma unroll
            for (int dt = 0; dt < 4; ++dt)
#pragma unroll
                for (int r = 0; r < 4; ++r) o[dt][r] *= alpha;
        }
        // P packed directly into the PV B-operand layout (phi-permuted V^T image)
        bf16x8 w[4];
        float rs = 0.f;
#pragma unroll
        for (int n = 0; n < 8; ++n) {
            const float p0 = exp2f(sc[n][0] - m), p1 = exp2f(sc[n][1] - m);
            const float p2 = exp2f(sc[n][2] - m), p3 = exp2f(sc[n][3] - m);
            rs += (p0 + p1) + (p2 + p3);
            const int wi = n >> 1, off = (n & 1) * 4;
            w[wi][off + 0] = (bf16_t)p0; w[wi][off + 1] = (bf16_t)p1;
            w[wi][off + 2] = (bf16_t)p2; w[wi][off + 3] = (bf16_t)p3;
        }
        l += rs;

        // ---- O^T += V^T P : P straight from registers, V^T from swizzled LDS ----
        __builtin_amdgcn_s_setprio(1);
#pragma unroll
        for (int ks = 0; ks < 4; ++ks) {
#pragma unroll
            for (int dt = 0; dt < 4; ++dt) {
                const int hw = (dt * 16 + lc) * 128 + ((((ks << 2) | lg) ^ lc7) << 3);
                const bf16x8 vb = *reinterpret_cast<const bf16x8*>(&Vt_lds[jb][hw]);
                o[dt] = __builtin_amdgcn_mfma_f32_16x16x32_bf16(vb, w[ks], o[dt], 0, 0, 0);
            }
        }
        __builtin_amdgcn_s_setprio(0);
        // no end-of-iteration barrier: next iteration's wait+barrier covers reuse
    }

    if (role == 0) {
        writePartialL();                       // front: tileL partial only
    } else {
        // back: tileS is complete -> divide and write directly
        float lr = l;
        lr += __shfl_xor(lr, 16);
        lr += __shfl_xor(lr, 32);
        const float inv = 1.0f / lr;
#pragma unroll
        for (int dt = 0; dt < 4; ++dt) {
            f32x4 val = { o[dt][0] * inv, o[dt][1] * inv, o[dt][2] * inv, o[dt][3] * inv };
            *reinterpret_cast<f32x4*>(Og + bbase + (size_t)qrow * D_H + dt * 16 + lg * 4) = val;
        }
    }
}

// ---------------- merge: 512 blocks x 256 threads (4 blocks per pair) ----------------
__global__ __launch_bounds__(256)
void merge_kernel(const float* __restrict__ Opart, const float* __restrict__ MLb,
                  float* __restrict__ Og)
{
    const int blk     = blockIdx.x;       // 0..511
    const int pairIdx = blk >> 2;         // 0..127  (= b*8 + p)
    const int sub     = blk & 3;
    const int b  = pairIdx >> 3, p = pairIdx & 7;
    const int qt = 15 - p;
    const int t  = threadIdx.x;
    const int q  = sub * 32 + (t >> 3);   // 0..127
    const int dc = (t & 7) * 8;           // 0,8,...,56

    const int slot0 = pairIdx * 2, slot1 = slot0 + 1;
    const float m0 = MLb[slot0 * 256 + q], l0 = MLb[slot0 * 256 + 128 + q];
    const float m1 = MLb[slot1 * 256 + q], l1 = MLb[slot1 * 256 + 128 + q];
    const float mt = fmaxf(m0, m1);
    const float a0 = exp2f(m0 - mt), a1 = exp2f(m1 - mt);
    const float inv = 1.0f / (l0 * a0 + l1 * a1);

    const float* o0 = Opart + (size_t)slot0 * (QB * D_H) + q * 64 + dc;
    const float* o1 = Opart + (size_t)slot1 * (QB * D_H) + q * 64 + dc;
    float* og = Og + (size_t)b * L_SEQ * D_H + (size_t)(qt * QB + q) * D_H + dc;
#pragma unroll
    for (int i = 0; i < 2; ++i) {
        const f32x4 v0 = *reinterpret_cast<const f32x4*>(o0 + i * 4);
        const f32x4 v1 = *reinterpret_cast<const f32x4*>(o1 + i * 4);
        f32x4 r;
#pragma unroll
        for (int k = 0; k < 4; ++k) r[k] = (v0[k] * a0 + v1[k] * a1) * inv;
        *reinterpret_cast<f32x4*>(og + i * 4) = r;
    }
}

// ---------------- fallback (no-ws path, round-6 kernel) ----------------
__global__ __launch_bounds__(256, 2)
void attn_fwd_fb(const float* __restrict__ Qg, const float* __restrict__ Kg,
                 const float* __restrict__ Vg, float* __restrict__ Og)
{
    const int lin  = blockIdx.x;
    const int xcd  = lin & 7;
    const int slot = lin >> 3;
    const int half = slot >> 5;
    const int qi   = slot & 31;
    const int b    = xcd * 2 + half;
    const int qt   = half ? qi : (31 - qi);

    const int tid  = threadIdx.x;
    const int lane = tid & 63;
    const int lg   = lane >> 4;
    const int lc   = lane & 15;
    const int lc7  = lc & 7;

    __shared__ __align__(16) bf16_t K_lds[2][KB * D_H];
    __shared__ __align__(16) bf16_t Vt_lds[2][D_H * KB];

    const size_t bbase = (size_t)b * L_SEQ * D_H;
    const int qrow = qt * 64 + (tid >> 6) * 16 + lc;
    bf16x8 qa[2];
#pragma unroll
    for (int h = 0; h < 2; ++h) {
        const float* qp = Qg + bbase + (size_t)qrow * D_H + h * 32 + lg * 8;
        const f32x4 f0 = *reinterpret_cast<const f32x4*>(qp);
        const f32x4 f1 = *reinterpret_cast<const f32x4*>(qp + 4);
        bf16x8 a;
#pragma unroll
        for (int j = 0; j < 4; ++j) { a[j] = (bf16_t)(f0[j] * QSCALE); a[4 + j] = (bf16_t)(f1[j] * QSCALE); }
        qa[h] = a;
    }
    f32x4 o[4];
#pragma unroll
    for (int dt = 0; dt < 4; ++dt) o[dt] = (f32x4){0.f, 0.f, 0.f, 0.f};
    float m = -1e30f, l = 0.f;
    const int nkt = (qt + 2) >> 1;
    const int vkb  = tid & 31;
    const int vdg  = tid >> 5;
    const int vpos = ((vkb >> 3) << 5) + ((vkb & 3) << 3) + (((vkb >> 2) & 1) << 2);
    f32x4 kreg[8], vreg[8];

    auto issueK = [&](int kt) {
        const int kbase = kt * KB;
#pragma unroll
        for (int i = 0; i < 4; ++i) {
            const int u = i * 256 + tid;
            const int r = u >> 3, ch = u & 7;
            const float* p = Kg + bbase + (size_t)(kbase + r) * D_H + ch * 8;
            kreg[2 * i]     = *reinterpret_cast<const f32x4*>(p);
            kreg[2 * i + 1] = *reinterpret_cast<const f32x4*>(p + 4);
        }
    };
    auto issueV = [&](int kt) {
        const int kbase = kt * KB;
#pragma unroll
        for (int d2 = 0; d2 < 2; ++d2)
#pragma unroll
            for (int i = 0; i < 4; ++i)
                vreg[d2 * 4 + i] = *reinterpret_cast<const f32x4*>(
                    Vg + bbase + (size_t)(kbase + vkb * 4 + i) * D_H + (vdg + d2 * 8) * 4);
    };
    auto writeK = [&](int buf) {
#pragma unroll
        for (int i = 0; i < 4; ++i) {
            const int u = i * 256 + tid;
            const int r = u >> 3, ch = u & 7;
            bf16x8 kk;
#pragma unroll
            for (int j = 0; j < 4; ++j) { kk[j] = (bf16_t)kreg[2 * i][j]; kk[4 + j] = (bf16_t)kreg[2 * i + 1][j]; }
            *reinterpret_cast<bf16x8*>(&K_lds[buf][r * 64 + ((ch ^ (r & 7)) << 3)]) = kk;
        }
    };
    auto writeV = [&](int buf) {
#pragma unroll
        for (int d2 = 0; d2 < 2; ++d2) {
            const int db = vdg + d2 * 8;
#pragma unroll
            for (int j = 0; j < 4; ++j) {
                const int d = db * 4 + j;
                bf16x4 cj = { (bf16_t)vreg[d2 * 4 + 0][j], (bf16_t)vreg[d2 * 4 + 1][j],
                              (bf16_t)vreg[d2 * 4 + 2][j], (bf16_t)vreg[d2 * 4 + 3][j] };
                const int hw = d * 128 + (((vpos >> 3) ^ (d & 7)) << 3) + (vpos & 7);
                *reinterpret_cast<bf16x4*>(&Vt_lds[buf][hw]) = cj;
            }
        }
    };

    issueK(0); issueV(0); writeK(0); writeV(0);
    __syncthreads();
    int cur = 0;
    for (int kt = 0; kt < nkt; ++kt) {
        const bool last = (kt == nkt - 1);
        const int kbase = kt * KB;
        if (!last) issueK(kt + 1);
        f32x4 sc[8];
#pragma unroll
        for (int n = 0; n < 8; ++n) {
            f32x4 acc = (f32x4){0.f, 0.f, 0.f, 0.f};
#pragma unroll
            for (int h = 0; h < 2; ++h) {
                const int hw = (n * 16 + lc) * 64 + ((((h << 2) | lg) ^ lc7) << 3);
                const bf16x8 kkb = *reinterpret_cast<const bf16x8*>(&K_lds[cur][hw]);
                acc = __builtin_amdgcn_mfma_f32_16x16x32_bf16(kkb, qa[h], acc, 0, 0, 0);
            }
            sc[n] = acc;
        }
        if (!last) issueV(kt + 1);
        if (last) {
#pragma unroll
            for (int n = 0; n < 8; ++n)
#pragma unroll
                for (int r = 0; r < 4; ++r)
                    if (kbase + n * 16 + lg * 4 + r > qrow) sc[n][r] = -1e30f;
        }
        float mxp = fmaxf(fmaxf(sc[0][0], sc[0][1]), fmaxf(sc[0][2], sc[0][3]));
#pragma unroll
        for (int n = 1; n < 8; ++n)
            mxp = fmaxf(mxp, fmaxf(fmaxf(sc[n][0], sc[n][1]), fmaxf(sc[n][2], sc[n][3])));
        if (!__all(mxp <= m + 8.0f)) {
            float mx = mxp;
            mx = fmaxf(mx, __shfl_xor(mx, 16));
            mx = fmaxf(mx, __shfl_xor(mx, 32));
            const float mn = fmaxf(m, mx);
            const float alpha = exp2f(m - mn);
            m = mn; l *= alpha;
#pragma unroll
            for (int dt = 0; dt < 4; ++dt)
#pragma unroll
                for (int r = 0; r < 4; ++r) o[dt][r] *= alpha;
        }
        bf16x8 w[4];
        float rs = 0.f;
#pragma unroll
        for (int n = 0; n < 8; ++n) {
            const float p0 = exp2f(sc[n][0] - m), p1 = exp2f(sc[n][1] - m);
            const float p2 = exp2f(sc[n][2] - m), p3 = exp2f(sc[n][3] - m);
            rs += (p0 + p1) + (p2 + p3);
            const int wi = n >> 1, off = (n & 1) * 4;
            w[wi][off + 0] = (bf16_t)p0; w[wi][off + 1] = (bf16_t)p1;
            w[wi][off + 2] = (bf16_t)p2; w[wi][off + 3] = (bf16_t)p3;
        }
        l += rs;
        if (!last) writeK(cur ^ 1);
#pragma unroll
        for (int ks = 0; ks < 4; ++ks) {
#pragma unroll
            for (int dt = 0; dt < 4; ++dt) {
                const int hw = (dt * 16 + lc) * 128 + ((((ks << 2) | lg) ^ lc7) << 3);
                const bf16x8 vb = *reinterpret_cast<const bf16x8*>(&Vt_lds[cur][hw]);
                o[dt] = __builtin_amdgcn_mfma_f32_16x16x32_bf16(vb, w[ks], o[dt], 0, 0, 0);
            }
        }
        if (!last) writeV(cur ^ 1);
        __syncthreads();
        cur ^= 1;
    }
    float lr = l;
    lr += __shfl_xor(lr, 16);
    lr += __shfl_xor(lr, 32);
    const float inv = 1.0f / lr;
#pragma unroll
    for (int dt = 0; dt < 4; ++dt) {
        f32x4 val = { o[dt][0] * inv, o[dt][1] * inv, o[dt][2] * inv, o[dt][3] * inv };
        *reinterpret_cast<f32x4*>(Og + bbase + (size_t)qrow * D_H + dt * 16 + lg * 4) = val;
    }
}

extern "C" void kernel_launch(void* const* d_in, const int* in_sizes, int n_in,
                              void* d_out, int out_size, void* d_ws, size_t ws_size,
                              hipStream_t stream)
{
    const float* Q = (const float*)d_in[0];
    const float* K = (const float*)d_in[1];
    const float* V = (const float*)d_in[2];
    float* O = (float*)d_out;

    const size_t img_bytes = 2 * IMG_ELEMS * sizeof(bf16_t);              // 8 MB
    const size_t opart_fl  = (size_t)B_SZ * 8 * 2 * (QB * D_H);           // 2M floats
    const size_t ml_fl     = (size_t)B_SZ * 8 * 2 * 256;                  // 64K floats
    const size_t need = img_bytes + (opart_fl + ml_fl) * sizeof(float);   // ~16.9 MB

    if (ws_size >= need) {
        bf16_t* Kimg  = (bf16_t*)d_ws;
        bf16_t* Vimg  = Kimg + IMG_ELEMS;
        float*  Opart = (float*)((char*)d_ws + img_bytes);
        float*  MLb   = Opart + opart_fl;
        preproc_kernel<<<dim3(NT128, B_SZ, 4), dim3(256), 0, stream>>>(K, V, Kimg, Vimg);
        attn_split_kernel<<<dim3(256), dim3(512), 0, stream>>>(Q, O, Kimg, Vimg, Opart, MLb);
        merge_kernel<<<dim3(512), dim3(256), 0, stream>>>(Opart, MLb, O);
    } else {
        attn_fwd_fb<<<dim3(512), dim3(256), 0, stream>>>(Q, K, V, O);
    }
}